// Round 7
// baseline (364.346 us; speedup 1.0000x reference)
//
#include <hip/hip_runtime.h>
#include <math.h>

#define Bsz   256
#define Nn    2048
#define Md    64
#define CSd   512
#define INPd  256
#define OUTd  256
#define KTOT  832      // INP + M + CS
#define PSTRIDE 128    // per-batch param block: erase[64] + add[64]
#define GSZ   524288   // 256*2048 gates elements (one split partial)
#define ZSPL  2        // K splits for gates GEMM
#define KZ    416      // K per split = 832/2 = 26*16

__device__ __forceinline__ float sigmoidf_(float x){ return 1.f/(1.f+expf(-x)); }
__device__ __forceinline__ float softplusf_(float x){ return fmaxf(x,0.f) + log1pf(expf(-fabsf(x))); }

__device__ __forceinline__ float4 loadA4(const float* __restrict__ x, const float* __restrict__ pr,
                                         const float* __restrict__ h, int row, int k){
  if (k < INPd)            return *(const float4*)&x[row*INPd + k];
  else if (k < INPd+Md)    return *(const float4*)&pr[row*Md + (k-INPd)];
  else                     return *(const float4*)&h[row*CSd + (k-INPd-Md)];
}
__device__ __forceinline__ float4 loadW4(const float* __restrict__ Wih, const float* __restrict__ Whh,
                                         int j, int k){
  if (k < INPd+Md)         return *(const float4*)&Wih[j*(INPd+Md) + k];
  else                     return *(const float4*)&Whh[j*CSd + (k-INPd-Md)];
}

// ---------------- Kernel 1: gates partials, split-K GEMM
// [256x832] @ [832x2048]^T, tile 64x64, BK=16, Z=2, 256 thr/blk, 4x4/thread
__global__ __launch_bounds__(256) void k_gates(
    const float* __restrict__ x, const float* __restrict__ prev_read, const float* __restrict__ h,
    const float* __restrict__ W_ih, const float* __restrict__ W_hh,
    float* __restrict__ partials)
{
  __shared__ __align__(16) float As[16][68];   // [k][row]
  __shared__ __align__(16) float Bs[16][68];   // [k][col]
  const int t = threadIdx.x;             // 0..255
  const int col0 = blockIdx.x * 64;
  const int row0 = blockIdx.y * 64;
  const int z    = blockIdx.z;
  const int lr = t >> 2;                 // 0..63 staging row/col
  const int kq = (t & 3) * 4;            // k offset within 16-slab
  const int tr = t >> 4, tc = t & 15;    // 16x16 compute grid
  const int arow = row0 + lr;
  const int bcol = col0 + lr;

  float acc[4][4] = {};
  int kb = z * KZ;
  float4 a  = loadA4(x, prev_read, h, arow, kb + kq);
  float4 bq = loadW4(W_ih, W_hh, bcol, kb + kq);

  for (int kc = 0; kc < 26; ++kc) {
    As[kq+0][lr] = a.x;  As[kq+1][lr] = a.y;  As[kq+2][lr] = a.z;  As[kq+3][lr] = a.w;
    Bs[kq+0][lr] = bq.x; Bs[kq+1][lr] = bq.y; Bs[kq+2][lr] = bq.z; Bs[kq+3][lr] = bq.w;
    __syncthreads();
    if (kc < 25) {
      int kn = kb + (kc+1)*16 + kq;
      a  = loadA4(x, prev_read, h, arow, kn);
      bq = loadW4(W_ih, W_hh, bcol, kn);
    }
    #pragma unroll
    for (int kk = 0; kk < 16; ++kk) {
      float av[4], bv[4];
      *(float4*)&av[0] = *(const float4*)&As[kk][tr*4];
      *(float4*)&bv[0] = *(const float4*)&Bs[kk][tc*4];
      #pragma unroll
      for (int i=0;i<4;++i)
        #pragma unroll
        for (int q=0;q<4;++q)
          acc[i][q] += av[i]*bv[q];
    }
    __syncthreads();
  }
  float* part = partials + (size_t)z * GSZ;
  #pragma unroll
  for (int i=0;i<4;++i) {
    int r = row0 + tr*4 + i;
    float4 v0 = {acc[i][0],acc[i][1],acc[i][2],acc[i][3]};
    *(float4*)&part[r*2048 + col0 + tc*4] = v0;
  }
}

// ---------------- Kernel 2: per-batch fused LSTM + heads + sim + addressing
// one block per batch, 1024 threads (16 waves)
__device__ __forceinline__ float hreduce(float val, float* red, int t, bool ismax){
  #pragma unroll
  for (int off=32; off; off>>=1)
    val = ismax ? fmaxf(val, __shfl_xor(val,off)) : val + __shfl_xor(val,off);
  __syncthreads();
  if ((t&63)==0) red[t>>6] = val;
  __syncthreads();
  int base = (t>>9)*8;            // per-half reduction (waves 0-7 / 8-15)
  float r = red[base];
  if (ismax) { for (int i=1;i<8;++i) r = fmaxf(r, red[base+i]); }
  else       { for (int i=1;i<8;++i) r += red[base+i]; }
  return r;
}

__global__ __launch_bounds__(1024) void k_fused(
    const float* __restrict__ partials, const float* __restrict__ c,
    const float* __restrict__ b_ih, const float* __restrict__ b_hh,
    const float* __restrict__ W_r, const float* __restrict__ b_r,
    const float* __restrict__ W_w, const float* __restrict__ b_w,
    const float* __restrict__ mem,
    const float* __restrict__ read_w, const float* __restrict__ write_w,
    float* __restrict__ h_new, float* __restrict__ c_new,
    float* __restrict__ w_read, float* __restrict__ w_write,
    float* __restrict__ params)
{
  __shared__ __align__(16) float hs[CSd];
  __shared__ float ob[268];
  __shared__ __align__(16) float sim[2][Nn];   // 16 KB; reused as wg
  __shared__ float red[16];
  __shared__ float sc[16];
  __shared__ __align__(16) float kvec[128];
  int b = blockIdx.x, t = threadIdx.x;

  // Hoisted P4 inputs: issue the prev-weights load NOW; consumed after P3.
  int which = t >> 9;          // 0 = read head, 1 = write head
  int tt = t & 511;
  const float* prev = which ? (write_w + b*Nn) : (read_w + b*Nn);
  float* outw       = which ? (w_write + b*Nn) : (w_read + b*Nn);
  float4 p4 = ((const float4*)prev)[tt];

  // --- P0: LSTM elementwise (threads 0..511)
  if (t < CSd) {
    float g[4];
    #pragma unroll
    for (int q = 0; q < 4; ++q) {
      int col = q*512 + t;
      float s = b_ih[col] + b_hh[col];
      #pragma unroll
      for (int sp = 0; sp < ZSPL; ++sp) s += partials[(size_t)sp*GSZ + b*2048 + col];
      g[q] = s;
    }
    float ig = sigmoidf_(g[0]);
    float fg = sigmoidf_(g[1]);
    float gg = tanhf(g[2]);
    float og = sigmoidf_(g[3]);
    float cn = fg * c[b*CSd + t] + ig * gg;
    float hn = og * tanhf(cn);
    c_new[b*CSd + t] = cn;
    h_new[b*CSd + t] = hn;
    hs[t] = hn;
  }
  __syncthreads();

  // --- P1: heads GEMV, wave-per-row (16 waves)
  int wave = t >> 6, lane = t & 63;
  for (int r = wave; r < 268; r += 16) {
    const float* wrow; float bias;
    if (r < 70) { wrow = W_r + r*CSd;      bias = b_r[r]; }
    else        { wrow = W_w + (r-70)*CSd; bias = b_w[r-70]; }
    float s = 0.f;
    #pragma unroll
    for (int i = 0; i < 8; ++i) s += wrow[i*64 + lane] * hs[i*64 + lane];
    #pragma unroll
    for (int off = 32; off; off >>= 1) s += __shfl_xor(s, off);
    if (lane == 0) ob[r] = s + bias;
  }
  __syncthreads();

  // --- P2: params (scalars to sc[], keys to kvec[], erase/add to global)
  if (wave == 0) {
    float v = ob[lane]; float sq = v*v;
    #pragma unroll
    for (int off = 32; off; off >>= 1) sq += __shfl_xor(sq, off);
    if (lane == 0) sc[6] = 1.f/(sqrtf(sq)+1e-8f);
  } else if (wave == 1) {
    float v = ob[70 + lane]; float sq = v*v;
    #pragma unroll
    for (int off = 32; off; off >>= 1) sq += __shfl_xor(sq, off);
    if (lane == 0) sc[13] = 1.f/(sqrtf(sq)+1e-8f);
  }
  if (t == 128) {
    sc[0] = softplusf_(ob[64]);
    sc[1] = sigmoidf_(ob[65]);
    float m3 = fmaxf(ob[66], fmaxf(ob[67], ob[68]));
    float e0=expf(ob[66]-m3), e1=expf(ob[67]-m3), e2=expf(ob[68]-m3);
    float es = e0+e1+e2;
    sc[2]=e0/es; sc[3]=e1/es; sc[4]=e2/es;
    sc[5] = 1.f + softplusf_(ob[69]);
  }
  if (t == 129) {
    sc[7] = softplusf_(ob[134]);
    sc[8] = sigmoidf_(ob[135]);
    float m3 = fmaxf(ob[136], fmaxf(ob[137], ob[138]));
    float e0=expf(ob[136]-m3), e1=expf(ob[137]-m3), e2=expf(ob[138]-m3);
    float es = e0+e1+e2;
    sc[9]=e0/es; sc[10]=e1/es; sc[11]=e2/es;
    sc[12] = 1.f + softplusf_(ob[139]);
  }
  if (t >= 256 && t < 384) {
    int i = t - 256;
    kvec[i] = (i < 64) ? ob[i] : ob[70 + (i-64)];
  }
  if (t >= 384 && t < 512) {
    int i = t - 384;
    params[b*PSTRIDE + i] = (i < 64) ? sigmoidf_(ob[140+i]) : ob[204 + (i-64)];
  }
  __syncthreads();

  // --- P3: cosine sim — coalesced 16 lanes/row + depth-8 software pipeline
  {
    int rr = t >> 4, chunk = t & 15;        // 64 rows/pass, 32 passes
    float4 kr = ((const float4*)kvec)[chunk];
    float4 kw = ((const float4*)(kvec+64))[chunk];
    float cr = sc[0]*sc[6];
    float cw = sc[7]*sc[13];
    const float4* m4 = (const float4*)mem + ((size_t)b*Nn)*16;
    float4 v0,v1,v2,v3,v4,v5,v6,v7;
    v0 = m4[(size_t)(0*64+rr)*16 + chunk];
    v1 = m4[(size_t)(1*64+rr)*16 + chunk];
    v2 = m4[(size_t)(2*64+rr)*16 + chunk];
    v3 = m4[(size_t)(3*64+rr)*16 + chunk];
    v4 = m4[(size_t)(4*64+rr)*16 + chunk];
    v5 = m4[(size_t)(5*64+rr)*16 + chunk];
    v6 = m4[(size_t)(6*64+rr)*16 + chunk];
    v7 = m4[(size_t)(7*64+rr)*16 + chunk];
#define SIMST(V,P) { \
    float ss = V.x*V.x + V.y*V.y + V.z*V.z + V.w*V.w; \
    float pr = V.x*kr.x + V.y*kr.y + V.z*kr.z + V.w*kr.w; \
    float pw = V.x*kw.x + V.y*kw.y + V.z*kw.z + V.w*kw.w; \
    _Pragma("unroll") \
    for (int off=8; off; off>>=1) { \
      ss += __shfl_xor(ss, off); \
      pr += __shfl_xor(pr, off); \
      pw += __shfl_xor(pw, off); \
    } \
    if (chunk == 0) { \
      int n = (P)*64 + rr; \
      float inv_nm = 1.f/(sqrtf(ss)+1e-8f); \
      sim[0][n] = cr * pr * inv_nm; \
      sim[1][n] = cw * pw * inv_nm; \
    } }
    for (int p = 0; p < 32; p += 8) {
      float4 c0=v0,c1=v1,c2=v2,c3=v3,c4=v4,c5=v5,c6=v6,c7=v7;
      if (p + 8 < 32) {
        v0 = m4[(size_t)((p+ 8)*64+rr)*16 + chunk];
        v1 = m4[(size_t)((p+ 9)*64+rr)*16 + chunk];
        v2 = m4[(size_t)((p+10)*64+rr)*16 + chunk];
        v3 = m4[(size_t)((p+11)*64+rr)*16 + chunk];
        v4 = m4[(size_t)((p+12)*64+rr)*16 + chunk];
        v5 = m4[(size_t)((p+13)*64+rr)*16 + chunk];
        v6 = m4[(size_t)((p+14)*64+rr)*16 + chunk];
        v7 = m4[(size_t)((p+15)*64+rr)*16 + chunk];
      }
      SIMST(c0,p)   SIMST(c1,p+1) SIMST(c2,p+2) SIMST(c3,p+3)
      SIMST(c4,p+4) SIMST(c5,p+5) SIMST(c6,p+6) SIMST(c7,p+7)
    }
#undef SIMST
  }
  __syncthreads();

  // --- P4: dual softmax/interp/shift/sharpen (half-block per head)
  {
    const float* S = sc + which*7;
    float g = S[1], s0 = S[2], s1 = S[3], s2 = S[4], gamma = S[5];
    float4 v4 = *(const float4*)&sim[which][tt*4];
    float v[4] = {v4.x, v4.y, v4.z, v4.w};
    float lmax = fmaxf(fmaxf(v[0],v[1]), fmaxf(v[2],v[3]));
    float mx = hreduce(lmax, red, t, true);
    float e[4]; float ps = 0.f;
    #pragma unroll
    for (int i=0;i<4;++i){ e[i] = expf(v[i]-mx); ps += e[i]; }
    float denom = hreduce(ps, red, t, false);
    float inv = 1.f/denom;
    float pv[4] = {p4.x, p4.y, p4.z, p4.w};
    float* wg = sim[which];
    #pragma unroll
    for (int i=0;i<4;++i){
      float wc = e[i]*inv;
      wg[tt*4+i] = g*wc + (1.f-g)*pv[i];
    }
    __syncthreads();
    float wp[4]; float psum = 0.f;
    #pragma unroll
    for (int i=0;i<4;++i){
      int n = tt*4+i;
      float wsv = s0*wg[(n+Nn-1)&(Nn-1)] + s1*wg[n] + s2*wg[(n+1)&(Nn-1)];
      wp[i] = wsv > 0.f ? __expf(gamma*__logf(wsv)) : 0.f;
      psum += wp[i];
    }
    float tot = hreduce(psum, red, t, false);
    float invt = 1.f/(tot + 1e-8f);
    float4 o4 = {wp[0]*invt, wp[1]*invt, wp[2]*invt, wp[3]*invt};
    ((float4*)outw)[tt] = o4;
  }
}

// ---------------- Kernel 3: per-batch memory update + read_vec + out GEMV
__global__ __launch_bounds__(1024) void k_mo(
    const float* __restrict__ mem, const float* __restrict__ params,
    const float* __restrict__ w_read, const float* __restrict__ w_write,
    const float* __restrict__ h_new,
    const float* __restrict__ W_o, const float* __restrict__ b_o,
    float* __restrict__ mem_new, float* __restrict__ read_vec, float* __restrict__ out)
{
  __shared__ __align__(16) float4 part[16][16];   // [wave][chunk]
  __shared__ __align__(16) float vbuf[576];
  int b = blockIdx.x, t = threadIdx.x;
  const float* P = params + b*PSTRIDE;
  int chunk = t & 15;
  int rr = t >> 4;                 // 0..63
  int wave = t >> 6, lane = t & 63;
  // erase/add read direct (same 16B broadcast within 16-lane group; L2-hot)
  float4 e4 = ((const float4*)P)[chunk];
  float4 a4 = ((const float4*)(P+64))[chunk];
  if (t < CSd) vbuf[t] = h_new[b*CSd + t];

  // --- P1: stream memory rows in pairs (128 rows/pass, 16 passes, unroll 4)
  const float4* m4 = (const float4*)mem     + ((size_t)b*Nn)*16;
  float4*       o4p = (float4*)mem_new      + ((size_t)b*Nn)*16;
  const float*  wwb = w_write + b*Nn;
  const float*  wrb = w_read  + b*Nn;
  float4 acc = {0.f,0.f,0.f,0.f};
  #pragma unroll 4
  for (int p = 0; p < 16; ++p) {
    int n1 = p*128 + rr, n2 = n1 + 64;
    float4 v1 = m4[(size_t)n1*16 + chunk];
    float4 v2 = m4[(size_t)n2*16 + chunk];
    float ww1 = wwb[n1], wr1 = wrb[n1];
    float ww2 = wwb[n2], wr2 = wrb[n2];
    float4 o1, o2;
    o1.x = v1.x*(1.f-ww1*e4.x) + ww1*a4.x;
    o1.y = v1.y*(1.f-ww1*e4.y) + ww1*a4.y;
    o1.z = v1.z*(1.f-ww1*e4.z) + ww1*a4.z;
    o1.w = v1.w*(1.f-ww1*e4.w) + ww1*a4.w;
    o2.x = v2.x*(1.f-ww2*e4.x) + ww2*a4.x;
    o2.y = v2.y*(1.f-ww2*e4.y) + ww2*a4.y;
    o2.z = v2.z*(1.f-ww2*e4.z) + ww2*a4.z;
    o2.w = v2.w*(1.f-ww2*e4.w) + ww2*a4.w;
    o4p[(size_t)n1*16 + chunk] = o1;
    o4p[(size_t)n2*16 + chunk] = o2;
    acc.x += wr1*v1.x + wr2*v2.x;
    acc.y += wr1*v1.y + wr2*v2.y;
    acc.z += wr1*v1.z + wr2*v2.z;
    acc.w += wr1*v1.w + wr2*v2.w;
  }
  #pragma unroll
  for (int off = 16; off <= 32; off <<= 1) {
    acc.x += __shfl_xor(acc.x, off);
    acc.y += __shfl_xor(acc.y, off);
    acc.z += __shfl_xor(acc.z, off);
    acc.w += __shfl_xor(acc.w, off);
  }
  if (lane < 16) part[wave][chunk] = acc;
  __syncthreads();

  // --- P2: finish read_vec reduction
  if (t < 16) {
    float4 s = part[0][t];
    #pragma unroll
    for (int w=1; w<16; ++w){ float4 q = part[w][t]; s.x+=q.x; s.y+=q.y; s.z+=q.z; s.w+=q.w; }
    *(float4*)&vbuf[512 + t*4] = s;
    *(float4*)&read_vec[b*64 + t*4] = s;
  }
  __syncthreads();

  // --- P3: out GEMV (16 waves x 16 cols)
  float vb[9];
  #pragma unroll
  for (int i = 0; i < 9; ++i) vb[i] = vbuf[i*64 + lane];
  for (int jj = 0; jj < 16; ++jj) {
    int cc = wave*16 + jj;
    const float* w = W_o + cc*576;
    float s = 0.f;
    #pragma unroll
    for (int i = 0; i < 9; ++i) s += w[i*64 + lane] * vb[i];
    #pragma unroll
    for (int off = 32; off; off >>= 1) s += __shfl_xor(s, off);
    if (lane == 0) out[b*OUTd + cc] = s + b_o[cc];
  }
}

extern "C" void kernel_launch(void* const* d_in, const int* in_sizes, int n_in,
                              void* d_out, int out_size, void* d_ws, size_t ws_size,
                              hipStream_t stream)
{
  const float* x         = (const float*)d_in[0];
  const float* memory    = (const float*)d_in[1];
  const float* h         = (const float*)d_in[2];
  const float* c         = (const float*)d_in[3];
  const float* read_w    = (const float*)d_in[4];
  const float* write_w   = (const float*)d_in[5];
  const float* prev_read = (const float*)d_in[6];
  const float* W_ih      = (const float*)d_in[7];
  const float* W_hh      = (const float*)d_in[8];
  const float* b_ih      = (const float*)d_in[9];
  const float* b_hh      = (const float*)d_in[10];
  const float* W_r       = (const float*)d_in[11];
  const float* b_r       = (const float*)d_in[12];
  const float* W_w       = (const float*)d_in[13];
  const float* b_w       = (const float*)d_in[14];
  const float* W_o       = (const float*)d_in[15];
  const float* b_o       = (const float*)d_in[16];

  float* out      = (float*)d_out;
  float* mem_new  = out + 256*256;
  float* h_new    = mem_new + (size_t)256*2048*64;
  float* c_new    = h_new + 256*512;
  float* w_read   = c_new + 256*512;
  float* w_write  = w_read + 256*2048;
  float* read_vec = w_write + 256*2048;

  float* ws       = (float*)d_ws;
  float* params   = ws;                      // 256*PSTRIDE floats
  float* partials = params + 256*PSTRIDE;    // ZSPL * GSZ floats (4 MB)

  k_gates<<<dim3(32,4,ZSPL), 256, 0, stream>>>(x, prev_read, h, W_ih, W_hh, partials);
  k_fused<<<256, 1024, 0, stream>>>(partials, c, b_ih, b_hh, W_r, b_r, W_w, b_w,
                                    memory, read_w, write_w,
                                    h_new, c_new, w_read, w_write, params);
  k_mo   <<<256, 1024, 0, stream>>>(memory, params, w_read, w_write, h_new,
                                    W_o, b_o, mem_new, read_vec, out);
}